// Round 1
// baseline (190.124 us; speedup 1.0000x reference)
//
#include <hip/hip_runtime.h>
#include <stdint.h>
#include <stddef.h>

#define MDIM 2048
#define KDIM 4096
#define NDIM 4096
// group size G = 128 along K

using bf16x8 = __attribute__((ext_vector_type(8))) short;   // 8 bf16 bit-patterns (4 VGPRs)
using f32x4  = __attribute__((ext_vector_type(4))) float;   // MFMA accumulator
using short8 = __attribute__((ext_vector_type(8))) short;

// fp32 -> bf16 (round-to-nearest-even), bit pattern in short
__device__ __forceinline__ short f2bf(float f) {
    union { float f; uint32_t u; } v; v.f = f;
    return (short)((v.u + 0x7fffu + ((v.u >> 16) & 1u)) >> 16);
}

// ---------------------------------------------------------------------------
// Pass 1a: cast x (M,K) fp32 -> bf16. 8 elems/thread, fully coalesced.
// ---------------------------------------------------------------------------
__global__ __launch_bounds__(256) void cast_x_bf16(const float* __restrict__ x,
                                                   short* __restrict__ y) {
    int i = (blockIdx.x * 256 + threadIdx.x) * 8;
    float4 a = *(const float4*)(x + i);
    float4 b = *(const float4*)(x + i + 4);
    short8 o;
    o[0] = f2bf(a.x); o[1] = f2bf(a.y); o[2] = f2bf(a.z); o[3] = f2bf(a.w);
    o[4] = f2bf(b.x); o[5] = f2bf(b.y); o[6] = f2bf(b.z); o[7] = f2bf(b.w);
    *(short8*)(y + i) = o;
}

// ---------------------------------------------------------------------------
// Pass 1b: dequant packed int4 -> bf16 W (N,K) row-major.
// Thread handles (n, k0..k0+7): reads 8 consecutive int32 of B-row n>>3,
// extracts nibble (n&7), scale s[k0/128, n] constant over the 8-chunk.
// Writes 16 B contiguous; consecutive threads -> consecutive chunks.
// ---------------------------------------------------------------------------
__global__ __launch_bounds__(256) void dequant_w(const int* __restrict__ Bq,
                                                 const float* __restrict__ s,
                                                 short* __restrict__ W) {
    int t  = blockIdx.x * 256 + threadIdx.x;
    int kc = t & 511;          // K/8 = 512 chunks per output row
    int n  = t >> 9;
    int k0 = kc * 8;
    int rowi = n >> 3;
    int sh   = (n & 7) * 4;
    const int* brow = Bq + (size_t)rowi * KDIM + k0;
    float sc = s[(k0 >> 7) * NDIM + n];    // group = k0/128
    int4 p0 = *(const int4*)(brow);
    int4 p1 = *(const int4*)(brow + 4);
    short8 o;
    o[0] = f2bf((float)(((p0.x >> sh) & 0xF) - 8) * sc);
    o[1] = f2bf((float)(((p0.y >> sh) & 0xF) - 8) * sc);
    o[2] = f2bf((float)(((p0.z >> sh) & 0xF) - 8) * sc);
    o[3] = f2bf((float)(((p0.w >> sh) & 0xF) - 8) * sc);
    o[4] = f2bf((float)(((p1.x >> sh) & 0xF) - 8) * sc);
    o[5] = f2bf((float)(((p1.y >> sh) & 0xF) - 8) * sc);
    o[6] = f2bf((float)(((p1.z >> sh) & 0xF) - 8) * sc);
    o[7] = f2bf((float)(((p1.w >> sh) & 0xF) - 8) * sc);
    *(short8*)(W + (size_t)n * KDIM + k0) = o;
}

// ---------------------------------------------------------------------------
// Pass 2: C = A(bf16, MxK) * W(bf16, NxK)^T, fp32 out.  m97-style structure:
// 128x128 block tile, BK=32, 4 waves (2x2), 4x4 16x16x32 MFMA per wave,
// global_load_lds width=16 staging, single-buffered LDS (16 KB).
// C/D layout: col = lane&15, row = (lane>>4)*4 + reg (m89/m91 verified).
// A/B frag:  row/col = lane&15, k = (lane>>4)*8 + j  -> one ds_read_b128.
// ---------------------------------------------------------------------------
__global__ __launch_bounds__(256) void gemm_bf16_bt(const short* __restrict__ A,
                                                    const short* __restrict__ W,
                                                    float* __restrict__ C) {
    __shared__ __align__(16) short As[128 * 32];
    __shared__ __align__(16) short Ws[128 * 32];

    const int tid  = threadIdx.x;
    const int lane = tid & 63;
    const int wave = tid >> 6;
    const int bm = blockIdx.y * 128;
    const int bn = blockIdx.x * 128;
    const int wm = (wave >> 1) * 64;   // wave tile: 64x64
    const int wn = (wave & 1) * 64;

    // staging: chunk c (0..511), 16 B each; LDS offset = c*16 bytes.
    // c = tid (issue 0) and tid+256 (issue 1): per-wave lds dest is
    // wave-uniform base + lane*16, matching global_load_lds semantics.
    const int c0 = tid, c1 = tid + 256;
    const size_t aoff0 = (size_t)(bm + (c0 >> 2)) * KDIM + (c0 & 3) * 8;
    const size_t aoff1 = (size_t)(bm + (c1 >> 2)) * KDIM + (c1 & 3) * 8;
    const size_t woff0 = (size_t)(bn + (c0 >> 2)) * KDIM + (c0 & 3) * 8;
    const size_t woff1 = (size_t)(bn + (c1 >> 2)) * KDIM + (c1 & 3) * 8;

    const int fr = lane & 15;          // fragment row (m or n)
    const int fk = (lane >> 4) * 8;    // fragment k offset within BK=32

    f32x4 acc[4][4] = {};

    for (int k0 = 0; k0 < KDIM; k0 += 32) {
        __builtin_amdgcn_global_load_lds(
            (const __attribute__((address_space(1))) uint32_t*)(A + aoff0 + k0),
            (__attribute__((address_space(3))) uint32_t*)(&As[c0 * 8]), 16, 0, 0);
        __builtin_amdgcn_global_load_lds(
            (const __attribute__((address_space(1))) uint32_t*)(A + aoff1 + k0),
            (__attribute__((address_space(3))) uint32_t*)(&As[c1 * 8]), 16, 0, 0);
        __builtin_amdgcn_global_load_lds(
            (const __attribute__((address_space(1))) uint32_t*)(W + woff0 + k0),
            (__attribute__((address_space(3))) uint32_t*)(&Ws[c0 * 8]), 16, 0, 0);
        __builtin_amdgcn_global_load_lds(
            (const __attribute__((address_space(1))) uint32_t*)(W + woff1 + k0),
            (__attribute__((address_space(3))) uint32_t*)(&Ws[c1 * 8]), 16, 0, 0);
        __syncthreads();   // compiler emits vmcnt(0) drain before barrier

        bf16x8 af[4], bfr[4];
#pragma unroll
        for (int i = 0; i < 4; i++)
            af[i] = *(const bf16x8*)&As[(wm + i * 16 + fr) * 32 + fk];
#pragma unroll
        for (int j = 0; j < 4; j++)
            bfr[j] = *(const bf16x8*)&Ws[(wn + j * 16 + fr) * 32 + fk];
#pragma unroll
        for (int i = 0; i < 4; i++)
#pragma unroll
            for (int j = 0; j < 4; j++)
                acc[i][j] = __builtin_amdgcn_mfma_f32_16x16x32_bf16(
                    af[i], bfr[j], acc[i][j], 0, 0, 0);
        __syncthreads();
    }

    // epilogue: D[row = (lane>>4)*4 + r][col = lane&15]
    const int col = bn + wn + (lane & 15);
    const int r0  = (lane >> 4) * 4;
#pragma unroll
    for (int i = 0; i < 4; i++)
#pragma unroll
        for (int j = 0; j < 4; j++)
#pragma unroll
            for (int r = 0; r < 4; r++)
                C[(size_t)(bm + wm + i * 16 + r0 + r) * NDIM + (col + j * 16)]
                    = acc[i][j][r];
}

// ---------------------------------------------------------------------------
extern "C" void kernel_launch(void* const* d_in, const int* in_sizes, int n_in,
                              void* d_out, int out_size, void* d_ws, size_t ws_size,
                              hipStream_t stream) {
    const float* x  = (const float*)d_in[0];
    const int*   Bq = (const int*)d_in[1];
    const float* s  = (const float*)d_in[2];
    float* out = (float*)d_out;

    // workspace: [0,16MB) x in bf16, [16MB,48MB) dequantized W in bf16
    short* xbf = (short*)d_ws;
    short* wbf = xbf + (size_t)MDIM * KDIM;

    hipLaunchKernelGGL(cast_x_bf16, dim3(MDIM * KDIM / (256 * 8)), dim3(256), 0,
                       stream, x, xbf);
    hipLaunchKernelGGL(dequant_w, dim3(NDIM * KDIM / (256 * 8)), dim3(256), 0,
                       stream, Bq, s, wbf);
    hipLaunchKernelGGL(gemm_bf16_bt, dim3(NDIM / 128, MDIM / 128), dim3(256), 0,
                       stream, xbf, wbf, out);
}